// Round 9
// baseline (465.240 us; speedup 1.0000x reference)
//
#include <hip/hip_runtime.h>

typedef unsigned short ushort_t;
typedef __attribute__((ext_vector_type(8))) short bf16x8;   // 8 bf16 = 4 VGPRs
typedef __attribute__((ext_vector_type(4))) float f32x4;

__device__ __forceinline__ float bflo(unsigned u) { return __uint_as_float(u << 16); }
__device__ __forceinline__ float bfhi(unsigned u) { return __uint_as_float(u & 0xffff0000u); }
__device__ __forceinline__ float bfu(ushort_t s)  { return __uint_as_float((unsigned)s << 16); }
__device__ __forceinline__ ushort_t f2bf(float f) {
    unsigned u = __float_as_uint(f);
    u = u + 0x7fffu + ((u >> 16) & 1u);   // RNE
    return (ushort_t)(u >> 16);
}
__device__ __forceinline__ void unpack8(uint4 v, float* f) {
    f[0]=bflo(v.x); f[1]=bfhi(v.x); f[2]=bflo(v.y); f[3]=bfhi(v.y);
    f[4]=bflo(v.z); f[5]=bfhi(v.z); f[6]=bflo(v.w); f[7]=bfhi(v.w);
}

// dtype-agnostic loads: f32 != 0 -> buffer holds float32, else bf16.
__device__ __forceinline__ float load1(const void* p, size_t i, int f32) {
    return f32 ? ((const float*)p)[i] : bfu(((const ushort_t*)p)[i]);
}
__device__ __forceinline__ void load8(const void* p, size_t i, int f32, float* f) {
    if (f32) {
        const float4 a = *(const float4*)((const float*)p + i);
        const float4 b = *(const float4*)((const float*)p + i + 4);
        f[0]=a.x; f[1]=a.y; f[2]=a.z; f[3]=a.w;
        f[4]=b.x; f[5]=b.y; f[6]=b.z; f[7]=b.w;
    } else {
        unpack8(*(const uint4*)((const ushort_t*)p + i), f);
    }
}
__device__ __forceinline__ void load4(const void* p, size_t i, int f32, float* f) {
    if (f32) {
        const float4 a = *(const float4*)((const float*)p + i);
        f[0]=a.x; f[1]=a.y; f[2]=a.z; f[3]=a.w;
    } else {
        const uint2 u = *(const uint2*)((const ushort_t*)p + i);
        f[0]=bflo(u.x); f[1]=bfhi(u.x); f[2]=bflo(u.y); f[3]=bfhi(u.y);
    }
}

// Inline dtype probe (wave-uniform): decode first 128 u16 halves of state1 as
// bf16. Real-bf16 randn stays <6; fp32 mantissa halves explode >1e6 w.p. ~1.
__device__ __forceinline__ int detect_f32(const ushort_t* s1h) {
    const int ln = threadIdx.x & 63;
    float v = fmaxf(fabsf(bfu(s1h[ln])), fabsf(bfu(s1h[ln + 64])));
    bool big = !(v <= 1e6f);               // NaN/Inf/large -> true
    return __ballot(big) != 0ull;
}

#define B_TOT 8192

__device__ __attribute__((aligned(16))) float    g_Wc1[384 * 4];
__device__ __attribute__((aligned(16))) float    g_Wv2[128 * 4];
__device__ __attribute__((aligned(16))) float    g_bc[4];
__device__ __attribute__((aligned(16))) float    g_t[B_TOT * 128];
__device__ __attribute__((aligned(16))) float    g_ogc[B_TOT * 4];
__device__ __attribute__((aligned(16))) ushort_t g_oe[B_TOT * 128];

// ---------------------------------------------------------------------------
// k_prep: single launch replacing k_pre + k_og (round 8 -> 9: 3 launches -> 2).
// Dependency-breaking recomputes make every block self-sufficient:
//   blocks    0..511 : ownt. t = own_e@M rewritten as (own_e@Wq)@Wk^T, so g_M
//                      (and the whole k_pre M-computation, 128 blocks) is gone.
//   blocks 512..1023 : grid. Epilogue's Wc1[256:384] slice (2 KB) self-computed
//                      in a prologue (W1[256:384]@W2).
//   blocks 1024,1025 : pre-lite (k_main's g_Wc1[0:256 for Wv2], g_Wv2, g_bc),
//                      adapted to 256 threads (both halves duplicate work;
//                      identical-value racing writes are benign).
// LDS union <= 33.6 KB -> 4 blocks/CU (same as round-8 k_og).
// ---------------------------------------------------------------------------
struct OwntA { float s0sh[256]; float wosh[2048]; float bosh[128]; }; // 9.5 KB
struct OwntSmem {
    union { OwntA a; float qT[128 * 18]; } u;  // qT overlays dead phase-A region
    float oesh[16 * 129];                      // 8.25 KB
    float Mt[32][128];                         // 16 KB (Wq tiles, phase B)
};                                             // 33.6 KB
struct GridSmem {
    float s1T[32][18];
    float wg[32][128];
    float part[32][16][4];
    float w2s[512];
    float wcsl[512];                           // self-computed Wc1[256:384]
};                                             // 30.5 KB
struct PreSmem { float w2_sh[512]; float wc1_mid[512]; float redc[128][4]; };

__global__ __launch_bounds__(256) void k_prep(
    const void* __restrict__ state0, const void* __restrict__ W_own,
    const void* __restrict__ b_own, const void* __restrict__ state1,
    const void* __restrict__ W_grid, const void* __restrict__ b_grid,
    const void* __restrict__ Wq, const void* __restrict__ Wk,
    const void* __restrict__ Wv, const void* __restrict__ W1,
    const void* __restrict__ b1, const void* __restrict__ W2,
    const void* __restrict__ b2, const ushort_t* __restrict__ s1h)
{
    __shared__ __attribute__((aligned(16))) char smem_raw[sizeof(OwntSmem)];
    const int tid = threadIdx.x;
    const int bxx = blockIdx.x;
    const int f32 = detect_f32(s1h);

    if (bxx < 512) {
        // ================= ownt: own_e, then t = (own_e@Wq)@Wk^T ==========
        OwntSmem& S = *reinterpret_cast<OwntSmem*>(smem_raw);
        const int b0 = bxx * 16;

        // ---- phase A: own_e = relu(state0@W_own + b_own) -> oesh, g_oe ----
        if (tid < 32) {
            float f[8]; load8(state0, (size_t)b0*16 + tid*8, f32, f);
            #pragma unroll
            for (int j = 0; j < 8; ++j) S.u.a.s0sh[tid*8 + j] = f[j];
        }
        {
            float f[8]; load8(W_own, (size_t)tid*8, f32, f);
            #pragma unroll
            for (int j = 0; j < 8; ++j) S.u.a.wosh[tid*8 + j] = f[j];
        }
        if (tid < 128) S.u.a.bosh[tid] = load1(b_own, tid, f32);
        __syncthreads();

        #pragma unroll
        for (int kk = 0; kk < 8; ++kk) {
            const int idx = tid + kk*256;
            const int bi = idx >> 7, h = idx & 127;
            float acc = S.u.a.bosh[h];
            #pragma unroll
            for (int d = 0; d < 16; ++d) acc = fmaf(S.u.a.s0sh[bi*16+d], S.u.a.wosh[d*128+h], acc);
            acc = fmaxf(acc, 0.f);
            S.oesh[bi*129 + h] = acc;
            g_oe[(size_t)(b0+bi)*128 + h] = f2bf(acc);
        }

        // ---- phase B: q = oesh @ Wq (tiled like the old M-loop) ----------
        const int bi0 = (tid >> 5) * 2;
        const int h0  = (tid & 31) * 4;
        float q00=0.f,q01=0.f,q02=0.f,q03=0.f,q10=0.f,q11=0.f,q12=0.f,q13=0.f;
        for (int kt = 0; kt < 128; kt += 32) {
            __syncthreads();
            #pragma unroll
            for (int c = 0; c < 4; ++c) {
                const int i = tid + c*256;
                const int kk = i >> 5;
                const int hh = (i & 31) * 4;
                float f[4];
                load4(Wq, (size_t)(kt+kk)*128 + hh, f32, f);
                *(float4*)&S.Mt[kk][hh] = make_float4(f[0], f[1], f[2], f[3]);
            }
            __syncthreads();
            #pragma unroll
            for (int k = 0; k < 32; ++k) {
                const float4 mv = *(const float4*)&S.Mt[k][h0];
                const float a0 = S.oesh[(bi0+0)*129 + kt + k];
                const float a1 = S.oesh[(bi0+1)*129 + kt + k];
                q00=fmaf(a0,mv.x,q00); q01=fmaf(a0,mv.y,q01); q02=fmaf(a0,mv.z,q02); q03=fmaf(a0,mv.w,q03);
                q10=fmaf(a1,mv.x,q10); q11=fmaf(a1,mv.y,q11); q12=fmaf(a1,mv.z,q12); q13=fmaf(a1,mv.w,q13);
            }
        }
        // u.a is dead (last read in phase A, >=2 barriers ago) -> qT overlay.
        // qT[h][b] = q[b][h], pad 18 (bank-spread; phase-C reads broadcast).
        {
            const float qq[2][4] = {{q00,q01,q02,q03},{q10,q11,q12,q13}};
            #pragma unroll
            for (int i = 0; i < 4; ++i)
                #pragma unroll
                for (int ib = 0; ib < 2; ++ib)
                    S.u.qT[(h0+i)*18 + (bi0+ib)] = qq[ib][i];
        }
        __syncthreads();

        // ---- phase C: t[b][j] = q[b]·Wk[j,:] (Wk rows streamed, L2-hot) ---
        {
            const int j  = tid >> 1;
            const int b8 = (tid & 1) * 8;
            float tacc[8] = {0.f,0.f,0.f,0.f,0.f,0.f,0.f,0.f};
            #pragma unroll
            for (int c = 0; c < 16; ++c) {
                float wf[8]; load8(Wk, (size_t)j*128 + c*8, f32, wf);
                #pragma unroll
                for (int jj = 0; jj < 8; ++jj) {
                    const int k = c*8 + jj;
                    #pragma unroll
                    for (int ib = 0; ib < 8; ++ib)
                        tacc[ib] = fmaf(wf[jj], S.u.qT[k*18 + b8 + ib], tacc[ib]);
                }
            }
            #pragma unroll
            for (int ib = 0; ib < 8; ++ib)
                g_t[(size_t)(b0 + b8 + ib)*128 + j] = tacc[ib];
        }
    } else if (bxx < 1024) {
        // ================= grid (self-computed Wc1[256:384] slice) ========
        GridSmem& S = *reinterpret_cast<GridSmem*>(smem_raw);
        const int b0 = (bxx - 512) * 16;

        // prologue: wcsl[h][j] = sum_m W1[256+h][m] * W2[m][j]
        for (int i = tid; i < 512; i += 256) S.w2s[i] = load1(W2, i, f32);
        __syncthreads();
        {
            const int r  = tid >> 1;
            const int jp = (tid & 1) * 2;
            float acc0 = 0.f, acc1 = 0.f;
            #pragma unroll
            for (int c = 0; c < 16; ++c) {
                float wf[8]; load8(W1, (size_t)(256 + r)*128 + c*8, f32, wf);
                #pragma unroll
                for (int jj = 0; jj < 8; ++jj) {
                    const int mm = c*8 + jj;
                    acc0 = fmaf(wf[jj], S.w2s[mm*4 + jp],     acc0);
                    acc1 = fmaf(wf[jj], S.w2s[mm*4 + jp + 1], acc1);
                }
            }
            S.wcsl[r*4 + jp]     = acc0;
            S.wcsl[r*4 + jp + 1] = acc1;
        }
        __syncthreads();

        const int bq = tid & 7;
        const int hq = tid >> 3;
        float a00=0.f,a01=0.f,a02=0.f,a03=0.f;
        float a10=0.f,a11=0.f,a12=0.f,a13=0.f;

        for (int kt = 0; kt < 512; kt += 32) {
            if (kt) __syncthreads();
            if (tid < 128) {
                const int bb = tid >> 3;
                const int kk = (tid & 7) * 4;
                float f[4];
                load4(state1, (size_t)(b0 + bb)*512 + kt + kk, f32, f);
                #pragma unroll
                for (int j = 0; j < 4; ++j) S.s1T[kk + j][bb] = f[j];
            }
            {
                #pragma unroll
                for (int c = 0; c < 4; ++c) {
                    const int i = tid + c*256;
                    const int kk = i >> 5;
                    const int hh = (i & 31) * 4;
                    float f[4];
                    load4(W_grid, (size_t)(kt + kk)*128 + hh, f32, f);
                    *(float4*)&S.wg[kk][hh] = make_float4(f[0], f[1], f[2], f[3]);
                }
            }
            __syncthreads();
            #pragma unroll 8
            for (int k = 0; k < 32; ++k) {
                const float x0 = S.s1T[k][bq*2 + 0];
                const float x1 = S.s1T[k][bq*2 + 1];
                const float4 w = *(const float4*)&S.wg[k][hq*4];
                a00=fmaf(x0,w.x,a00); a01=fmaf(x0,w.y,a01); a02=fmaf(x0,w.z,a02); a03=fmaf(x0,w.w,a03);
                a10=fmaf(x1,w.x,a10); a11=fmaf(x1,w.y,a11); a12=fmaf(x1,w.z,a12); a13=fmaf(x1,w.w,a13);
            }
        }

        float accs[2][4] = {{a00,a01,a02,a03},{a10,a11,a12,a13}};
        float pr[2][4] = {{0,0,0,0},{0,0,0,0}};
        #pragma unroll
        for (int jh = 0; jh < 4; ++jh) {
            const int h = hq*4 + jh;
            const float bg = load1(b_grid, h, f32);
            const float4 wc = *(const float4*)&S.wcsl[h*4];
            #pragma unroll
            for (int ib = 0; ib < 2; ++ib) {
                const float og = fmaxf(accs[ib][jh] + bg, 0.f);
                pr[ib][0] = fmaf(og, wc.x, pr[ib][0]);
                pr[ib][1] = fmaf(og, wc.y, pr[ib][1]);
                pr[ib][2] = fmaf(og, wc.z, pr[ib][2]);
                pr[ib][3] = fmaf(og, wc.w, pr[ib][3]);
            }
        }
        __syncthreads();
        #pragma unroll
        for (int j = 0; j < 4; ++j) {
            S.part[hq][bq*2+0][j] = pr[0][j];
            S.part[hq][bq*2+1][j] = pr[1][j];
        }
        __syncthreads();
        if (tid < 64) {
            const int bb = tid >> 2, j = tid & 3;
            float s = 0.f;
            #pragma unroll
            for (int q = 0; q < 32; ++q) s += S.part[q][bb][j];
            g_ogc[(size_t)(b0 + bb)*4 + j] = s;
        }
    } else {
        // ================= pre-lite (blocks 1024, 1025) ===================
        PreSmem& S = *reinterpret_cast<PreSmem*>(smem_raw);
        const int rbase = (bxx == 1024) ? 0 : 128;
        for (int i = tid; i < 512; i += 256) S.w2_sh[i] = load1(W2, i, f32);
        __syncthreads();

        const int rt = tid & 127;          // both halves duplicate (benign)
        const int r = rbase + rt;
        float a[4] = {0.f, 0.f, 0.f, 0.f};
        #pragma unroll
        for (int c = 0; c < 16; ++c) {
            float f[8]; load8(W1, (size_t)r*128 + c*8, f32, f);
            #pragma unroll
            for (int j = 0; j < 8; ++j) {
                const int p = c*8 + j;
                #pragma unroll
                for (int q = 0; q < 4; ++q) a[q] = fmaf(f[j], S.w2_sh[p*4+q], a[q]);
            }
        }
        #pragma unroll
        for (int q = 0; q < 4; ++q) g_Wc1[r*4+q] = a[q];

        if (bxx == 1025) {
            #pragma unroll
            for (int q = 0; q < 4; ++q) S.wc1_mid[rt*4+q] = a[q];
            __syncthreads();
            float v[4] = {0.f, 0.f, 0.f, 0.f};
            #pragma unroll
            for (int c = 0; c < 16; ++c) {
                float f[8]; load8(Wv, (size_t)rt*128 + c*8, f32, f);
                #pragma unroll
                for (int j = 0; j < 8; ++j) {
                    const int i2 = c*8 + j;
                    #pragma unroll
                    for (int q = 0; q < 4; ++q) v[q] = fmaf(f[j], S.wc1_mid[i2*4+q], v[q]);
                }
            }
            #pragma unroll
            for (int q = 0; q < 4; ++q) g_Wv2[rt*4+q] = v[q];

            const float bv = load1(b1, rt, f32);
            #pragma unroll
            for (int q = 0; q < 4; ++q) S.redc[rt][q] = bv * S.w2_sh[rt*4+q];
            __syncthreads();
            for (int s = 64; s > 0; s >>= 1) {
                if (tid < s) {
                    #pragma unroll
                    for (int q = 0; q < 4; ++q) S.redc[tid][q] += S.redc[tid+s][q];
                }
                __syncthreads();
            }
            if (tid < 4) g_bc[tid] = S.redc[0][tid] + load1(b2, tid, f32);
        }
    }
}

// ---------------------------------------------------------------------------
// K4 v2 (VERBATIM — best measured: 71.5us, VGPR 64, occ 36%). Rounds 3-7
// established: every VALU-cutting restructure raised VGPR, cut occupancy, and
// lost net time (64/36%/71.7 -> 88/20%/85.5 -> 208/11%/129.5). The compiler's
// regalloc of THIS source (rematerializing A from global across the softmax)
// is the best allocation found. Do not edit.
// ---------------------------------------------------------------------------
__global__ __launch_bounds__(256) void k_main(
    const void* __restrict__ state2, const void* __restrict__ W_intr,
    const void* __restrict__ b_intr, const ushort_t* __restrict__ s1h,
    void* __restrict__ out_raw)
{
    __shared__ __attribute__((aligned(16))) ushort_t wib[128 * 40]; // [h][k] bf16
    const int tid = threadIdx.x;
    const int f32 = detect_f32(s1h);

    // stage W_intr^T (coalesced read [d][h], transposed write), pad k=20..31
    #pragma unroll
    for (int c = 0; c < 10; ++c) {
        const int idx = c*256 + tid;          // idx = d*128 + h
        const int d = idx >> 7, h = idx & 127;
        wib[h*40 + d] = f32 ? f2bf(((const float*)W_intr)[idx])
                            : ((const ushort_t*)W_intr)[idx];
    }
    if (tid < 128) {
        #pragma unroll
        for (int k = 20; k < 32; ++k) wib[tid*40 + k] = 0;
    }
    __syncthreads();

    const int wv = tid >> 6, ln = tid & 63, lq = ln >> 4, lc = ln & 15;
    const int b = blockIdx.x * 4 + wv;

    // per-lane constants: bias (h = th*16+lc) and t (pre-scaled by 1/sqrt(H))
    float bi_r[8], t_r[8];
    #pragma unroll
    for (int th = 0; th < 8; ++th) {
        bi_r[th] = load1(b_intr, th*16 + lc, f32);
        t_r[th]  = g_t[(size_t)b*128 + th*16 + lc] * 0.08838834764831845f;
    }

    // A fragments (row n = i*16+lc, cols k = lq*8..+7; k>=20 register zeros)
    bf16x8 A[8];
    unsigned msk[8];
    if (!f32) {
        const ushort_t* s2 = (const ushort_t*)state2;
        #pragma unroll
        for (int i = 0; i < 8; ++i) {
            const size_t rb = ((size_t)b*128 + i*16 + lc)*20 + lq*8;
            uint2 p0 = make_uint2(0u, 0u), p1 = make_uint2(0u, 0u);
            if (lq < 2)       { p0 = *(const uint2*)(s2 + rb); p1 = *(const uint2*)(s2 + rb + 4); }
            else if (lq == 2) { p0 = *(const uint2*)(s2 + rb); }
            union { bf16x8 v; uint2 u[2]; } cv;
            cv.u[0] = p0; cv.u[1] = p1;
            A[i] = cv.v;
            float s = bflo(p0.x)+bfhi(p0.x)+bflo(p0.y)+bfhi(p0.y)
                    + bflo(p1.x)+bfhi(p1.x)+bflo(p1.y)+bfhi(p1.y);
            s += __shfl_xor(s, 16);
            s += __shfl_xor(s, 32);
            msk[i] = (unsigned)(__ballot(s != 0.f) & 0xffffull);
        }
    } else {
        const float* s2 = (const float*)state2;
        #pragma unroll
        for (int i = 0; i < 8; ++i) {
            const size_t rb = ((size_t)b*128 + i*16 + lc)*20 + lq*8;
            float f[8] = {0.f,0.f,0.f,0.f,0.f,0.f,0.f,0.f};
            if (lq < 2) {
                const float4 a4 = *(const float4*)(s2 + rb);
                const float4 b4 = *(const float4*)(s2 + rb + 4);
                f[0]=a4.x; f[1]=a4.y; f[2]=a4.z; f[3]=a4.w;
                f[4]=b4.x; f[5]=b4.y; f[6]=b4.z; f[7]=b4.w;
            } else if (lq == 2) {
                const float4 a4 = *(const float4*)(s2 + rb);
                f[0]=a4.x; f[1]=a4.y; f[2]=a4.z; f[3]=a4.w;
            }
            union { bf16x8 v; ushort_t h[8]; } cv;
            float s = 0.f;
            #pragma unroll
            for (int j = 0; j < 8; ++j) { cv.h[j] = f2bf(f[j]); s += f[j]; }
            A[i] = cv.v;
            s += __shfl_xor(s, 16);
            s += __shfl_xor(s, 32);
            msk[i] = (unsigned)(__ballot(s != 0.f) & 0xffffull);
        }
    }

    const f32x4 zf = {0.f, 0.f, 0.f, 0.f};

    // ---- pass 1: score[n] = relu(s2@W_intr + b) . t --------------------
    float sc[8][4];
    #pragma unroll
    for (int i = 0; i < 8; ++i)
        #pragma unroll
        for (int r = 0; r < 4; ++r) sc[i][r] = 0.f;

    #pragma unroll
    for (int th = 0; th < 8; ++th) {
        const bf16x8 Bv = *(const bf16x8*)&wib[(th*16 + lc)*40 + lq*8];
        #pragma unroll
        for (int i = 0; i < 8; ++i) {
            const f32x4 acc = __builtin_amdgcn_mfma_f32_16x16x32_bf16(A[i], Bv, zf, 0, 0, 0);
            #pragma unroll
            for (int r = 0; r < 4; ++r)
                sc[i][r] = fmaf(fmaxf(acc[r] + bi_r[th], 0.f), t_r[th], sc[i][r]);
        }
    }
    // reduce over the 16 h-lanes (lc)
    #pragma unroll
    for (int off = 1; off < 16; off <<= 1)
        #pragma unroll
        for (int i = 0; i < 8; ++i)
            #pragma unroll
            for (int r = 0; r < 4; ++r)
                sc[i][r] += __shfl_xor(sc[i][r], off);

    // ---- softmax over n (masked), fully in registers -------------------
    float m = -1e30f;
    #pragma unroll
    for (int i = 0; i < 8; ++i)
        #pragma unroll
        for (int r = 0; r < 4; ++r)
            if ((msk[i] >> (lq*4 + r)) & 1) m = fmaxf(m, sc[i][r]);
    m = fmaxf(m, __shfl_xor(m, 16));
    m = fmaxf(m, __shfl_xor(m, 32));

    float den = 0.f;
    #pragma unroll
    for (int i = 0; i < 8; ++i)
        #pragma unroll
        for (int r = 0; r < 4; ++r) {
            float e = 0.f;
            if ((msk[i] >> (lq*4 + r)) & 1) e = __expf(fmaxf(sc[i][r] - m, -80.f));
            sc[i][r] = e;
            den += e;
        }
    den += __shfl_xor(den, 16);
    den += __shfl_xor(den, 32);
    const float rden = (den > 0.f) ? (1.f / den) : 0.f;
    #pragma unroll
    for (int i = 0; i < 8; ++i)
        #pragma unroll
        for (int r = 0; r < 4; ++r) sc[i][r] *= rden;   // sc = alpha

    // ---- pass 2: out4 += (alpha . x_e) * Wv2, recomputing x_e ----------
    float o4[4] = {0.f, 0.f, 0.f, 0.f};
    #pragma unroll
    for (int th = 0; th < 8; ++th) {
        const bf16x8 Bv = *(const bf16x8*)&wib[(th*16 + lc)*40 + lq*8];
        float up = 0.f;
        #pragma unroll
        for (int i = 0; i < 8; ++i) {
            const f32x4 acc = __builtin_amdgcn_mfma_f32_16x16x32_bf16(A[i], Bv, zf, 0, 0, 0);
            #pragma unroll
            for (int r = 0; r < 4; ++r)
                up = fmaf(sc[i][r], fmaxf(acc[r] + bi_r[th], 0.f), up);
        }
        const float4 w2 = *(const float4*)&g_Wv2[(th*16 + lc)*4];
        o4[0] = fmaf(up, w2.x, o4[0]);
        o4[1] = fmaf(up, w2.y, o4[1]);
        o4[2] = fmaf(up, w2.z, o4[2]);
        o4[3] = fmaf(up, w2.w, o4[3]);
    }

    // ---- own_e @ Wc1[0:128] term (h = ln and ln+64) --------------------
    {
        const float oe0 = bfu(g_oe[(size_t)b*128 + ln]);
        const float oe1 = bfu(g_oe[(size_t)b*128 + 64 + ln]);
        const float4 wA = *(const float4*)&g_Wc1[ln*4];
        const float4 wB = *(const float4*)&g_Wc1[(64 + ln)*4];
        o4[0] += oe0*wA.x + oe1*wB.x;
        o4[1] += oe0*wA.y + oe1*wB.y;
        o4[2] += oe0*wA.z + oe1*wB.z;
        o4[3] += oe0*wA.w + oe1*wB.w;
    }

    // ---- 64-lane reduce + write ---------------------------------------
    #pragma unroll
    for (int off = 1; off < 64; off <<= 1)
        #pragma unroll
        for (int q = 0; q < 4; ++q)
            o4[q] += __shfl_xor(o4[q], off);

    if (ln == 0) {
        const float4 og = *(const float4*)&g_ogc[(size_t)b*4];
        const float v0 = g_bc[0] + og.x + o4[0];
        const float v1 = g_bc[1] + og.y + o4[1];
        const float v2 = g_bc[2] + og.z + o4[2];
        const float v3 = g_bc[3] + og.w + o4[3];
        const float l0 = fminf(fmaxf(v0, -20.f), 2.f);
        const float l1 = fminf(fmaxf(v1, -20.f), 2.f);
        const float l2 = fminf(fmaxf(v2, -20.f), 2.f);
        const float l3 = fminf(fmaxf(v3, -20.f), 2.f);
        if (f32) {
            float* of = (float*)out_raw;
            *(float4*)&of[(size_t)b*4] = make_float4(v0, v1, v2, v3);
            *(float4*)&of[((size_t)B_TOT + b)*4] = make_float4(l0, l1, l2, l3);
        } else {
            ushort_t* os = (ushort_t*)out_raw;
            uint2 mw, lw;
            mw.x = (unsigned)f2bf(v0) | ((unsigned)f2bf(v1) << 16);
            mw.y = (unsigned)f2bf(v2) | ((unsigned)f2bf(v3) << 16);
            lw.x = (unsigned)f2bf(l0) | ((unsigned)f2bf(l1) << 16);
            lw.y = (unsigned)f2bf(l2) | ((unsigned)f2bf(l3) << 16);
            *(uint2*)&os[(size_t)b*4] = mw;
            *(uint2*)&os[((size_t)B_TOT + b)*4] = lw;
        }
    }
}

// ---------------------------------------------------------------------------
extern "C" void kernel_launch(void* const* d_in, const int* in_sizes, int n_in,
                              void* d_out, int out_size, void* d_ws, size_t ws_size,
                              hipStream_t stream)
{
    (void)in_sizes; (void)n_in; (void)out_size; (void)d_ws; (void)ws_size;
    const void* state0 = d_in[0];
    const void* state1 = d_in[1];
    const void* state2 = d_in[2];
    const void* W_own  = d_in[3];
    const void* b_own  = d_in[4];
    const void* W_intr = d_in[5];
    const void* b_intr = d_in[6];
    const void* W_grid = d_in[7];
    const void* b_grid = d_in[8];
    const void* Wq     = d_in[9];
    const void* Wk     = d_in[10];
    const void* Wv     = d_in[11];
    const void* W1     = d_in[12];
    const void* b1     = d_in[13];
    const void* W2     = d_in[14];
    const void* b2     = d_in[15];
    const ushort_t* s1h = (const ushort_t*)state1;

    k_prep <<<dim3(1026), dim3(256), 0, stream>>>(state0, W_own, b_own,
                                                  state1, W_grid, b_grid,
                                                  Wq, Wk, Wv, W1, b1, W2, b2, s1h);
    k_main <<<dim3(2048), dim3(256), 0, stream>>>(state2, W_intr, b_intr, s1h, d_out);
}

// Round 10
// 280.026 us; speedup vs baseline: 1.6614x; 1.6614x over previous
//
#include <hip/hip_runtime.h>

typedef unsigned short ushort_t;
typedef __attribute__((ext_vector_type(8))) short bf16x8;   // 8 bf16 = 4 VGPRs
typedef __attribute__((ext_vector_type(4))) float f32x4;

__device__ __forceinline__ float bflo(unsigned u) { return __uint_as_float(u << 16); }
__device__ __forceinline__ float bfhi(unsigned u) { return __uint_as_float(u & 0xffff0000u); }
__device__ __forceinline__ float bfu(ushort_t s)  { return __uint_as_float((unsigned)s << 16); }
__device__ __forceinline__ ushort_t f2bf(float f) {
    unsigned u = __float_as_uint(f);
    u = u + 0x7fffu + ((u >> 16) & 1u);   // RNE
    return (ushort_t)(u >> 16);
}
__device__ __forceinline__ void unpack8(uint4 v, float* f) {
    f[0]=bflo(v.x); f[1]=bfhi(v.x); f[2]=bflo(v.y); f[3]=bfhi(v.y);
    f[4]=bflo(v.z); f[5]=bfhi(v.z); f[6]=bflo(v.w); f[7]=bfhi(v.w);
}

// dtype-agnostic loads: f32 != 0 -> buffer holds float32, else bf16.
__device__ __forceinline__ float load1(const void* p, size_t i, int f32) {
    return f32 ? ((const float*)p)[i] : bfu(((const ushort_t*)p)[i]);
}
__device__ __forceinline__ void load8(const void* p, size_t i, int f32, float* f) {
    if (f32) {
        const float4 a = *(const float4*)((const float*)p + i);
        const float4 b = *(const float4*)((const float*)p + i + 4);
        f[0]=a.x; f[1]=a.y; f[2]=a.z; f[3]=a.w;
        f[4]=b.x; f[5]=b.y; f[6]=b.z; f[7]=b.w;
    } else {
        unpack8(*(const uint4*)((const ushort_t*)p + i), f);
    }
}
__device__ __forceinline__ void load4(const void* p, size_t i, int f32, float* f) {
    if (f32) {
        const float4 a = *(const float4*)((const float*)p + i);
        f[0]=a.x; f[1]=a.y; f[2]=a.z; f[3]=a.w;
    } else {
        const uint2 u = *(const uint2*)((const ushort_t*)p + i);
        f[0]=bflo(u.x); f[1]=bfhi(u.x); f[2]=bflo(u.y); f[3]=bfhi(u.y);
    }
}

// Inline dtype probe (wave-uniform): decode first 128 u16 halves of state1 as
// bf16. Real-bf16 randn stays <6; fp32 mantissa halves explode >1e6 w.p. ~1.
__device__ __forceinline__ int detect_f32(const ushort_t* s1h) {
    const int ln = threadIdx.x & 63;
    float v = fmaxf(fabsf(bfu(s1h[ln])), fabsf(bfu(s1h[ln + 64])));
    bool big = !(v <= 1e6f);               // NaN/Inf/large -> true
    return __ballot(big) != 0ull;
}

#define B_TOT 8192

__device__ __attribute__((aligned(16))) float    g_M[128 * 128];
__device__ __attribute__((aligned(16))) float    g_Wc1[384 * 4];
__device__ __attribute__((aligned(16))) float    g_Wv2[128 * 4];
__device__ __attribute__((aligned(16))) float    g_bc[4];
__device__ __attribute__((aligned(16))) float    g_t[B_TOT * 128];
__device__ __attribute__((aligned(16))) float    g_ogc[B_TOT * 4];
__device__ __attribute__((aligned(16))) ushort_t g_oe[B_TOT * 128];

// ---------------------------------------------------------------------------
// K1: precompute M = Wq@Wk^T, Wc1 = W1@W2, Wv2 = Wv@Wc1[128:256], bc = b1@W2+b2
// (Round-9 lesson: the mega-merge of this into k_og spilled to scratch —
//  VGPR 256, WRITE 322MB, 286us. Keep the 3-launch structure of round 8.)
// ---------------------------------------------------------------------------
__global__ __launch_bounds__(128) void k_pre(
    const void* __restrict__ Wq, const void* __restrict__ Wk,
    const void* __restrict__ Wv, const void* __restrict__ W1,
    const void* __restrict__ b1, const void* __restrict__ W2,
    const void* __restrict__ b2, const ushort_t* __restrict__ s1h)
{
    __shared__ float wq_sh[128];
    __shared__ float w2_sh[512];
    __shared__ float wc1_mid[512];
    __shared__ float redc[128][4];
    const int tid = threadIdx.x;
    const int bx = blockIdx.x;
    const int f32 = detect_f32(s1h);

    if (bx < 128) {
        wq_sh[tid] = load1(Wq, bx*128 + tid, f32);
        __syncthreads();
        float acc = 0.f;
        #pragma unroll
        for (int c = 0; c < 16; ++c) {
            float f[8]; load8(Wk, (size_t)tid*128 + c*8, f32, f);
            #pragma unroll
            for (int j = 0; j < 8; ++j) acc = fmaf(wq_sh[c*8+j], f[j], acc);
        }
        g_M[bx*128 + tid] = acc;
    } else {
        const int rbase = (bx == 128) ? 0 : ((bx == 129) ? 128 : 256);
        for (int i = tid; i < 512; i += 128) w2_sh[i] = load1(W2, i, f32);
        __syncthreads();

        const int r = rbase + tid;
        float a[4] = {0.f, 0.f, 0.f, 0.f};
        #pragma unroll
        for (int c = 0; c < 16; ++c) {
            float f[8]; load8(W1, (size_t)r*128 + c*8, f32, f);
            #pragma unroll
            for (int j = 0; j < 8; ++j) {
                const int p = c*8 + j;
                #pragma unroll
                for (int q = 0; q < 4; ++q) a[q] = fmaf(f[j], w2_sh[p*4+q], a[q]);
            }
        }
        #pragma unroll
        for (int q = 0; q < 4; ++q) g_Wc1[r*4+q] = a[q];

        if (bx == 129) {
            #pragma unroll
            for (int q = 0; q < 4; ++q) wc1_mid[tid*4+q] = a[q];
            __syncthreads();
            float v[4] = {0.f, 0.f, 0.f, 0.f};
            #pragma unroll
            for (int c = 0; c < 16; ++c) {
                float f[8]; load8(Wv, (size_t)tid*128 + c*8, f32, f);
                #pragma unroll
                for (int j = 0; j < 8; ++j) {
                    const int i2 = c*8 + j;
                    #pragma unroll
                    for (int q = 0; q < 4; ++q) v[q] = fmaf(f[j], wc1_mid[i2*4+q], v[q]);
                }
            }
            #pragma unroll
            for (int q = 0; q < 4; ++q) g_Wv2[tid*4+q] = v[q];

            const float bv = load1(b1, tid, f32);
            #pragma unroll
            for (int q = 0; q < 4; ++q) redc[tid][q] = bv * w2_sh[tid*4+q];
            __syncthreads();
            for (int s = 64; s > 0; s >>= 1) {
                if (tid < s) {
                    #pragma unroll
                    for (int q = 0; q < 4; ++q) redc[tid][q] += redc[tid+s][q];
                }
                __syncthreads();
            }
            if (tid < 4) g_bc[tid] = redc[0][tid] + load1(b2, tid, f32);
        }
    }
}

// ---------------------------------------------------------------------------
// K2+K3 merged (k_og). Round-9 change vs round 8: GRID FIRST (blocks 0..511),
// ownt second (512..1023). Grid is the longer branch (16 barrier-paired
// K-iterations); dispatching it first starts the critical path earlier and
// lets the shorter ownt blocks fill the tail. Bodies are byte-identical.
// ---------------------------------------------------------------------------
struct OwntSmem {
    float s0sh[16*16];
    float wosh[16*128];
    float bosh[128];
    float oesh[16*129];
    float Mt[32][128];
};
struct GridSmem {
    float s1T[32][18];
    float wg[32][128];
    float part[32][16][4];
};

__global__ __launch_bounds__(256) void k_og(
    const void* __restrict__ state0, const void* __restrict__ W_own,
    const void* __restrict__ b_own, const void* __restrict__ state1,
    const void* __restrict__ W_grid, const void* __restrict__ b_grid,
    const ushort_t* __restrict__ s1h)
{
    __shared__ __attribute__((aligned(16))) char smem_raw[
        sizeof(OwntSmem) > sizeof(GridSmem) ? sizeof(OwntSmem) : sizeof(GridSmem)];
    const int tid = threadIdx.x;
    const int bxx = blockIdx.x;
    const int f32 = detect_f32(s1h);

    if (bxx < 512) {
        // ================= k_grid body (longer pole — dispatched first) ====
        GridSmem& S = *reinterpret_cast<GridSmem*>(smem_raw);
        const int b0 = bxx * 16;

        const int bq = tid & 7;
        const int hq = tid >> 3;
        float a00=0.f,a01=0.f,a02=0.f,a03=0.f;
        float a10=0.f,a11=0.f,a12=0.f,a13=0.f;

        for (int kt = 0; kt < 512; kt += 32) {
            if (kt) __syncthreads();
            if (tid < 128) {
                const int bb = tid >> 3;
                const int kk = (tid & 7) * 4;
                float f[4];
                load4(state1, (size_t)(b0 + bb)*512 + kt + kk, f32, f);
                #pragma unroll
                for (int j = 0; j < 4; ++j) S.s1T[kk + j][bb] = f[j];
            }
            {
                #pragma unroll
                for (int c = 0; c < 4; ++c) {
                    const int i = tid + c*256;
                    const int kk = i >> 5;
                    const int hh = (i & 31) * 4;
                    float f[4];
                    load4(W_grid, (size_t)(kt + kk)*128 + hh, f32, f);
                    *(float4*)&S.wg[kk][hh] = make_float4(f[0], f[1], f[2], f[3]);
                }
            }
            __syncthreads();
            #pragma unroll 8
            for (int k = 0; k < 32; ++k) {
                const float x0 = S.s1T[k][bq*2 + 0];
                const float x1 = S.s1T[k][bq*2 + 1];
                const float4 w = *(const float4*)&S.wg[k][hq*4];
                a00=fmaf(x0,w.x,a00); a01=fmaf(x0,w.y,a01); a02=fmaf(x0,w.z,a02); a03=fmaf(x0,w.w,a03);
                a10=fmaf(x1,w.x,a10); a11=fmaf(x1,w.y,a11); a12=fmaf(x1,w.z,a12); a13=fmaf(x1,w.w,a13);
            }
        }

        float accs[2][4] = {{a00,a01,a02,a03},{a10,a11,a12,a13}};
        float pr[2][4] = {{0,0,0,0},{0,0,0,0}};
        #pragma unroll
        for (int jh = 0; jh < 4; ++jh) {
            const int h = hq*4 + jh;
            const float bg = load1(b_grid, h, f32);
            const float4 wc = *(const float4*)&g_Wc1[(256 + h)*4];
            #pragma unroll
            for (int ib = 0; ib < 2; ++ib) {
                const float og = fmaxf(accs[ib][jh] + bg, 0.f);
                pr[ib][0] = fmaf(og, wc.x, pr[ib][0]);
                pr[ib][1] = fmaf(og, wc.y, pr[ib][1]);
                pr[ib][2] = fmaf(og, wc.z, pr[ib][2]);
                pr[ib][3] = fmaf(og, wc.w, pr[ib][3]);
            }
        }
        __syncthreads();
        #pragma unroll
        for (int j = 0; j < 4; ++j) {
            S.part[hq][bq*2+0][j] = pr[0][j];
            S.part[hq][bq*2+1][j] = pr[1][j];
        }
        __syncthreads();
        if (tid < 64) {
            const int bb = tid >> 2, j = tid & 3;
            float s = 0.f;
            #pragma unroll
            for (int q = 0; q < 32; ++q) s += S.part[q][bb][j];
            g_ogc[(size_t)(b0 + bb)*4 + j] = s;
        }
    } else {
        // ================= k_ownt body =================
        OwntSmem& S = *reinterpret_cast<OwntSmem*>(smem_raw);
        const int b0 = (bxx - 512) * 16;

        if (tid < 32) {
            float f[8]; load8(state0, (size_t)b0*16 + tid*8, f32, f);
            #pragma unroll
            for (int j = 0; j < 8; ++j) S.s0sh[tid*8 + j] = f[j];
        }
        {
            float f[8]; load8(W_own, (size_t)tid*8, f32, f);
            #pragma unroll
            for (int j = 0; j < 8; ++j) S.wosh[tid*8 + j] = f[j];
        }
        if (tid < 128) S.bosh[tid] = load1(b_own, tid, f32);
        __syncthreads();

        #pragma unroll
        for (int kk = 0; kk < 8; ++kk) {
            const int idx = tid + kk*256;
            const int bi = idx >> 7, h = idx & 127;
            float acc = S.bosh[h];
            #pragma unroll
            for (int d = 0; d < 16; ++d) acc = fmaf(S.s0sh[bi*16+d], S.wosh[d*128+h], acc);
            acc = fmaxf(acc, 0.f);
            S.oesh[bi*129 + h] = acc;
            g_oe[(size_t)(b0+bi)*128 + h] = f2bf(acc);
        }

        const int bi0 = (tid >> 5) * 2;
        const int h0  = (tid & 31) * 4;
        float t00=0.f,t01=0.f,t02=0.f,t03=0.f,t10=0.f,t11=0.f,t12=0.f,t13=0.f;
        for (int kt = 0; kt < 128; kt += 32) {
            __syncthreads();
            #pragma unroll
            for (int c = 0; c < 4; ++c) {
                const int i = tid + c*256;
                const int kk = i >> 5;
                const int hh = (i & 31) * 4;
                *(float4*)&S.Mt[kk][hh] = *(const float4*)&g_M[(size_t)(kt+kk)*128 + hh];
            }
            __syncthreads();
            #pragma unroll
            for (int k = 0; k < 32; ++k) {
                const float4 mv = *(const float4*)&S.Mt[k][h0];
                const float a0 = S.oesh[(bi0+0)*129 + kt + k];
                const float a1 = S.oesh[(bi0+1)*129 + kt + k];
                t00=fmaf(a0,mv.x,t00); t01=fmaf(a0,mv.y,t01); t02=fmaf(a0,mv.z,t02); t03=fmaf(a0,mv.w,t03);
                t10=fmaf(a1,mv.x,t10); t11=fmaf(a1,mv.y,t11); t12=fmaf(a1,mv.z,t12); t13=fmaf(a1,mv.w,t13);
            }
        }
        *(float4*)&g_t[(size_t)(b0+bi0+0)*128 + h0] = make_float4(t00,t01,t02,t03);
        *(float4*)&g_t[(size_t)(b0+bi0+1)*128 + h0] = make_float4(t10,t11,t12,t13);
    }
}

// ---------------------------------------------------------------------------
// K4 v2 (VERBATIM — best measured: 71.5us, VGPR 64, occ 36%). Rounds 3-7
// established: every VALU-cutting restructure raised VGPR, cut occupancy, and
// lost net time (64/36%/71.7 -> 88/20%/85.5 -> 208/11%/129.5). The compiler's
// regalloc of THIS source (rematerializing A from global across the softmax)
// is the best allocation found. Do not edit.
// ---------------------------------------------------------------------------
__global__ __launch_bounds__(256) void k_main(
    const void* __restrict__ state2, const void* __restrict__ W_intr,
    const void* __restrict__ b_intr, const ushort_t* __restrict__ s1h,
    void* __restrict__ out_raw)
{
    __shared__ __attribute__((aligned(16))) ushort_t wib[128 * 40]; // [h][k] bf16
    const int tid = threadIdx.x;
    const int f32 = detect_f32(s1h);

    // stage W_intr^T (coalesced read [d][h], transposed write), pad k=20..31
    #pragma unroll
    for (int c = 0; c < 10; ++c) {
        const int idx = c*256 + tid;          // idx = d*128 + h
        const int d = idx >> 7, h = idx & 127;
        wib[h*40 + d] = f32 ? f2bf(((const float*)W_intr)[idx])
                            : ((const ushort_t*)W_intr)[idx];
    }
    if (tid < 128) {
        #pragma unroll
        for (int k = 20; k < 32; ++k) wib[tid*40 + k] = 0;
    }
    __syncthreads();

    const int wv = tid >> 6, ln = tid & 63, lq = ln >> 4, lc = ln & 15;
    const int b = blockIdx.x * 4 + wv;

    // per-lane constants: bias (h = th*16+lc) and t (pre-scaled by 1/sqrt(H))
    float bi_r[8], t_r[8];
    #pragma unroll
    for (int th = 0; th < 8; ++th) {
        bi_r[th] = load1(b_intr, th*16 + lc, f32);
        t_r[th]  = g_t[(size_t)b*128 + th*16 + lc] * 0.08838834764831845f;
    }

    // A fragments (row n = i*16+lc, cols k = lq*8..+7; k>=20 register zeros)
    bf16x8 A[8];
    unsigned msk[8];
    if (!f32) {
        const ushort_t* s2 = (const ushort_t*)state2;
        #pragma unroll
        for (int i = 0; i < 8; ++i) {
            const size_t rb = ((size_t)b*128 + i*16 + lc)*20 + lq*8;
            uint2 p0 = make_uint2(0u, 0u), p1 = make_uint2(0u, 0u);
            if (lq < 2)       { p0 = *(const uint2*)(s2 + rb); p1 = *(const uint2*)(s2 + rb + 4); }
            else if (lq == 2) { p0 = *(const uint2*)(s2 + rb); }
            union { bf16x8 v; uint2 u[2]; } cv;
            cv.u[0] = p0; cv.u[1] = p1;
            A[i] = cv.v;
            float s = bflo(p0.x)+bfhi(p0.x)+bflo(p0.y)+bfhi(p0.y)
                    + bflo(p1.x)+bfhi(p1.x)+bflo(p1.y)+bfhi(p1.y);
            s += __shfl_xor(s, 16);
            s += __shfl_xor(s, 32);
            msk[i] = (unsigned)(__ballot(s != 0.f) & 0xffffull);
        }
    } else {
        const float* s2 = (const float*)state2;
        #pragma unroll
        for (int i = 0; i < 8; ++i) {
            const size_t rb = ((size_t)b*128 + i*16 + lc)*20 + lq*8;
            float f[8] = {0.f,0.f,0.f,0.f,0.f,0.f,0.f,0.f};
            if (lq < 2) {
                const float4 a4 = *(const float4*)(s2 + rb);
                const float4 b4 = *(const float4*)(s2 + rb + 4);
                f[0]=a4.x; f[1]=a4.y; f[2]=a4.z; f[3]=a4.w;
                f[4]=b4.x; f[5]=b4.y; f[6]=b4.z; f[7]=b4.w;
            } else if (lq == 2) {
                const float4 a4 = *(const float4*)(s2 + rb);
                f[0]=a4.x; f[1]=a4.y; f[2]=a4.z; f[3]=a4.w;
            }
            union { bf16x8 v; ushort_t h[8]; } cv;
            float s = 0.f;
            #pragma unroll
            for (int j = 0; j < 8; ++j) { cv.h[j] = f2bf(f[j]); s += f[j]; }
            A[i] = cv.v;
            s += __shfl_xor(s, 16);
            s += __shfl_xor(s, 32);
            msk[i] = (unsigned)(__ballot(s != 0.f) & 0xffffull);
        }
    }

    const f32x4 zf = {0.f, 0.f, 0.f, 0.f};

    // ---- pass 1: score[n] = relu(s2@W_intr + b) . t --------------------
    float sc[8][4];
    #pragma unroll
    for (int i = 0; i < 8; ++i)
        #pragma unroll
        for (int r = 0; r < 4; ++r) sc[i][r] = 0.f;

    #pragma unroll
    for (int th = 0; th < 8; ++th) {
        const bf16x8 Bv = *(const bf16x8*)&wib[(th*16 + lc)*40 + lq*8];
        #pragma unroll
        for (int i = 0; i < 8; ++i) {
            const f32x4 acc = __builtin_amdgcn_mfma_f32_16x16x32_bf16(A[i], Bv, zf, 0, 0, 0);
            #pragma unroll
            for (int r = 0; r < 4; ++r)
                sc[i][r] = fmaf(fmaxf(acc[r] + bi_r[th], 0.f), t_r[th], sc[i][r]);
        }
    }
    // reduce over the 16 h-lanes (lc)
    #pragma unroll
    for (int off = 1; off < 16; off <<= 1)
        #pragma unroll
        for (int i = 0; i < 8; ++i)
            #pragma unroll
            for (int r = 0; r < 4; ++r)
                sc[i][r] += __shfl_xor(sc[i][r], off);

    // ---- softmax over n (masked), fully in registers -------------------
    float m = -1e30f;
    #pragma unroll
    for (int i = 0; i < 8; ++i)
        #pragma unroll
        for (int r = 0; r < 4; ++r)
            if ((msk[i] >> (lq*4 + r)) & 1) m = fmaxf(m, sc[i][r]);
    m = fmaxf(m, __shfl_xor(m, 16));
    m = fmaxf(m, __shfl_xor(m, 32));

    float den = 0.f;
    #pragma unroll
    for (int i = 0; i < 8; ++i)
        #pragma unroll
        for (int r = 0; r < 4; ++r) {
            float e = 0.f;
            if ((msk[i] >> (lq*4 + r)) & 1) e = __expf(fmaxf(sc[i][r] - m, -80.f));
            sc[i][r] = e;
            den += e;
        }
    den += __shfl_xor(den, 16);
    den += __shfl_xor(den, 32);
    const float rden = (den > 0.f) ? (1.f / den) : 0.f;
    #pragma unroll
    for (int i = 0; i < 8; ++i)
        #pragma unroll
        for (int r = 0; r < 4; ++r) sc[i][r] *= rden;   // sc = alpha

    // ---- pass 2: out4 += (alpha . x_e) * Wv2, recomputing x_e ----------
    float o4[4] = {0.f, 0.f, 0.f, 0.f};
    #pragma unroll
    for (int th = 0; th < 8; ++th) {
        const bf16x8 Bv = *(const bf16x8*)&wib[(th*16 + lc)*40 + lq*8];
        float up = 0.f;
        #pragma unroll
        for (int i = 0; i < 8; ++i) {
            const f32x4 acc = __builtin_amdgcn_mfma_f32_16x16x32_bf16(A[i], Bv, zf, 0, 0, 0);
            #pragma unroll
            for (int r = 0; r < 4; ++r)
                up = fmaf(sc[i][r], fmaxf(acc[r] + bi_r[th], 0.f), up);
        }
        const float4 w2 = *(const float4*)&g_Wv2[(th*16 + lc)*4];
        o4[0] = fmaf(up, w2.x, o4[0]);
        o4[1] = fmaf(up, w2.y, o4[1]);
        o4[2] = fmaf(up, w2.z, o4[2]);
        o4[3] = fmaf(up, w2.w, o4[3]);
    }

    // ---- own_e @ Wc1[0:128] term (h = ln and ln+64) --------------------
    {
        const float oe0 = bfu(g_oe[(size_t)b*128 + ln]);
        const float oe1 = bfu(g_oe[(size_t)b*128 + 64 + ln]);
        const float4 wA = *(const float4*)&g_Wc1[ln*4];
        const float4 wB = *(const float4*)&g_Wc1[(64 + ln)*4];
        o4[0] += oe0*wA.x + oe1*wB.x;
        o4[1] += oe0*wA.y + oe1*wB.y;
        o4[2] += oe0*wA.z + oe1*wB.z;
        o4[3] += oe0*wA.w + oe1*wB.w;
    }

    // ---- 64-lane reduce + write ---------------------------------------
    #pragma unroll
    for (int off = 1; off < 64; off <<= 1)
        #pragma unroll
        for (int q = 0; q < 4; ++q)
            o4[q] += __shfl_xor(o4[q], off);

    if (ln == 0) {
        const float4 og = *(const float4*)&g_ogc[(size_t)b*4];
        const float v0 = g_bc[0] + og.x + o4[0];
        const float v1 = g_bc[1] + og.y + o4[1];
        const float v2 = g_bc[2] + og.z + o4[2];
        const float v3 = g_bc[3] + og.w + o4[3];
        const float l0 = fminf(fmaxf(v0, -20.f), 2.f);
        const float l1 = fminf(fmaxf(v1, -20.f), 2.f);
        const float l2 = fminf(fmaxf(v2, -20.f), 2.f);
        const float l3 = fminf(fmaxf(v3, -20.f), 2.f);
        if (f32) {
            float* of = (float*)out_raw;
            *(float4*)&of[(size_t)b*4] = make_float4(v0, v1, v2, v3);
            *(float4*)&of[((size_t)B_TOT + b)*4] = make_float4(l0, l1, l2, l3);
        } else {
            ushort_t* os = (ushort_t*)out_raw;
            uint2 mw, lw;
            mw.x = (unsigned)f2bf(v0) | ((unsigned)f2bf(v1) << 16);
            mw.y = (unsigned)f2bf(v2) | ((unsigned)f2bf(v3) << 16);
            lw.x = (unsigned)f2bf(l0) | ((unsigned)f2bf(l1) << 16);
            lw.y = (unsigned)f2bf(l2) | ((unsigned)f2bf(l3) << 16);
            *(uint2*)&os[(size_t)b*4] = mw;
            *(uint2*)&os[((size_t)B_TOT + b)*4] = lw;
        }
    }
}

// ---------------------------------------------------------------------------
extern "C" void kernel_launch(void* const* d_in, const int* in_sizes, int n_in,
                              void* d_out, int out_size, void* d_ws, size_t ws_size,
                              hipStream_t stream)
{
    (void)in_sizes; (void)n_in; (void)out_size; (void)d_ws; (void)ws_size;
    const void* state0 = d_in[0];
    const void* state1 = d_in[1];
    const void* state2 = d_in[2];
    const void* W_own  = d_in[3];
    const void* b_own  = d_in[4];
    const void* W_intr = d_in[5];
    const void* b_intr = d_in[6];
    const void* W_grid = d_in[7];
    const void* b_grid = d_in[8];
    const void* Wq     = d_in[9];
    const void* Wk     = d_in[10];
    const void* Wv     = d_in[11];
    const void* W1     = d_in[12];
    const void* b1     = d_in[13];
    const void* W2     = d_in[14];
    const void* b2     = d_in[15];
    const ushort_t* s1h = (const ushort_t*)state1;

    k_pre  <<<dim3(131),  dim3(128), 0, stream>>>(Wq, Wk, Wv, W1, b1, W2, b2, s1h);
    k_og   <<<dim3(1024), dim3(256), 0, stream>>>(state0, W_own, b_own, state1, W_grid, b_grid, s1h);
    k_main <<<dim3(2048), dim3(256), 0, stream>>>(state2, W_intr, b_intr, s1h, d_out);
}